// Round 11
// baseline (417.357 us; speedup 1.0000x reference)
//
#include <hip/hip_runtime.h>
#include <stdint.h>

// VectorQuantizer — z:(16,256,64,64) f32 -> 65536 rows of 256; emb:(1024,256) f32.
// d_out: q[16777216] | vq_loss[1] | idx_as_float[65536]
//
// R11: 16-wave MFMA argmin (4 waves/SIMD vs R10's 2), K-step 32, bijective
// bank-permuted B staging (R10's B-reads were 4-way conflicted: g=(addr>>4)&7
// took 4/8 values). Same hi/lo-split 3-product math + margin worklist fixup.

typedef __attribute__((ext_vector_type(8))) short short8;
typedef __attribute__((ext_vector_type(16))) float f32x16;

#define THR_MARGIN 2e-3f

__device__ __forceinline__ unsigned short f2bf(float f) {
    const unsigned int x = __float_as_uint(f);
    return (unsigned short)((x + 0x7FFFu + ((x >> 16) & 1u)) >> 16);
}
__device__ __forceinline__ float bf2f(unsigned short h) {
    return __uint_as_float(((unsigned int)h) << 16);
}
__device__ __forceinline__ void gload16(const void* gp, void* lp) {
    __builtin_amdgcn_global_load_lds(
        (const __attribute__((address_space(1))) void*)gp,
        (__attribute__((address_space(3))) void*)lp, 16, 0, 0);
}

// ---------------- kernel 0: e prep — eh/el bf16 split + fp32 norms + wlcnt=0 ----
__global__ __launch_bounds__(256)
void eprep_kernel(const float* __restrict__ emb, unsigned short* __restrict__ eh_g,
                  unsigned short* __restrict__ el_g, float* __restrict__ enorm,
                  int* __restrict__ wlcnt) {
    const int code = blockIdx.x;
    const int t = threadIdx.x;
    if (code == 0 && t == 0) wlcnt[0] = 0;
    const float v = emb[code * 256 + t];
    const unsigned short h = f2bf(v);
    eh_g[code * 256 + t] = h;
    el_g[code * 256 + t] = f2bf(v - bf2f(h));
    float s = v * v;
#pragma unroll
    for (int o = 32; o > 0; o >>= 1) s += __shfl_xor(s, o);
    __shared__ float red[4];
    if ((t & 63) == 0) red[t >> 6] = s;
    __syncthreads();
    if (t == 0) enorm[code] = (red[0] + red[1]) + (red[2] + red[3]);
}

// ---------------- kernel 1: MFMA argmin (16 waves, K-step 32) ----------------
// 1024 thr = 16 waves; block = 64 rows x 1024 codes, 4 passes of 256 codes,
// each pass 8 K-slices of 32. wave w: rg=w&1 (32 rows), cg=w>>1 (32 codes).
// B slice LDS slot: ks*8K + c*32 + ((h ^ ((c>>2)&1))<<4)  == t*16 at staging.

#define STAGE(S, B) { \
    const int p_ = (S) >> 3, q_ = (S) & 7; \
    const size_t so_ = ssrc0 + (size_t)p_ * 65536 + (size_t)q_ * 32; \
    gload16(eh_g + so_, &bsl[B][t * 16]); \
    gload16(el_g + so_, &bsl[B][16384 + t * 16]); }

__global__ __launch_bounds__(1024, 4)
void argmin_kernel(const float* __restrict__ z, const unsigned short* __restrict__ eh_g,
                   const unsigned short* __restrict__ el_g, const float* __restrict__ enorm_g,
                   float* __restrict__ idx_out, float* __restrict__ zn_g,
                   int* __restrict__ wl, int* __restrict__ wlcnt) {
    __shared__ unsigned short zh[16384];  // 64 rows: byte = row*512 + (k*2 ^ ((row&7)<<4))
    __shared__ unsigned short zl[16384];
    __shared__ char bsl[2][32768];        // [h 16K | l 16K] per buffer
    __shared__ float znbuf[64];
    __shared__ float m_b1[8][64];
    __shared__ int   m_i1[8][64];
    __shared__ float m_b2[8][64];

    const int t = threadIdx.x;
    const int l = t & 63;
    const int hi = l >> 5, l32 = l & 31;
    const int w = t >> 6;
    const int rg = w & 1, cg = w >> 1;

    // staging decode (bijective bank permute: khalf = (t&1)^((t>>3)&1))
    const int sc  = (t & 511) >> 1;
    const int sks = t >> 9;
    const int shi = (t & 1) ^ ((t >> 3) & 1);
    const size_t ssrc0 = (size_t)sc * 256 + sks * 16 + shi * 8;

    const float* zblk = z + (size_t)blockIdx.x * 16384;

    STAGE(0, 0)   // slice-0 DMA overlaps the A-staging VALU work below

    // ---- A staging: fp32 -> bf16 hi/lo swizzled LDS + per-row |z|^2 ----
    {
        const int row = t >> 4;
        const int kk0 = (t & 15) * 16;
        float ps = 0.f;
#pragma unroll
        for (int i = 0; i < 4; ++i) {
            const int kk = kk0 + i * 4;
            const float4 v = *reinterpret_cast<const float4*>(zblk + row * 256 + kk);
            ushort4 hv, lv;
            hv.x = f2bf(v.x); lv.x = f2bf(v.x - bf2f(hv.x));
            hv.y = f2bf(v.y); lv.y = f2bf(v.y - bf2f(hv.y));
            hv.z = f2bf(v.z); lv.z = f2bf(v.z - bf2f(hv.z));
            hv.w = f2bf(v.w); lv.w = f2bf(v.w - bf2f(hv.w));
            const int boff = row * 512 + ((kk << 1) ^ ((row & 7) << 4));
            *reinterpret_cast<ushort4*>((char*)zh + boff) = hv;
            *reinterpret_cast<ushort4*>((char*)zl + boff) = lv;
            ps = fmaf(v.x, v.x, fmaf(v.y, v.y, fmaf(v.z, v.z, fmaf(v.w, v.w, ps))));
        }
        ps += __shfl_xor(ps, 1);
        ps += __shfl_xor(ps, 2);
        ps += __shfl_xor(ps, 4);
        ps += __shfl_xor(ps, 8);
        if ((l & 15) == 0) { znbuf[row] = ps; zn_g[blockIdx.x * 64 + row] = ps; }
    }

    asm volatile("s_waitcnt vmcnt(0)" ::: "memory");
    __syncthreads();   // A-LDS + znbuf + B slice 0 ready

    f32x16 acc1, acc2;
#pragma unroll
    for (int j = 0; j < 16; ++j) { acc1[j] = 0.f; acc2[j] = 0.f; }
    float stb1[16]; int sti1[16]; float stb2[16];
#pragma unroll
    for (int r = 0; r < 16; ++r) { stb1[r] = 3.4e38f; sti1[r] = 0; stb2[r] = 3.4e38f; }

    const int arow = rg * 32 + l32;
    const int abyte = arow * 512;
    const int aswz = (arow & 7) << 4;
    const int bbase = (cg * 32 + l32) * 32 + ((((l32 >> 2) & 1) ^ hi) << 4);

#pragma unroll 1
    for (int s = 0; s < 32; ++s) {
        const int b = s & 1;
        const int q = s & 7;
        if (s < 31) {
            STAGE(s + 1, b ^ 1)
            asm volatile("s_waitcnt vmcnt(2)" ::: "memory");
        } else {
            asm volatile("s_waitcnt vmcnt(0)" ::: "memory");
        }
        asm volatile("s_barrier" ::: "memory");
        __builtin_amdgcn_sched_barrier(0);

        __builtin_amdgcn_s_setprio(1);
#pragma unroll
        for (int ks = 0; ks < 2; ++ks) {
            const int akb = (q * 64 + ks * 32 + hi * 16) ^ aswz;
            const short8 ah = *reinterpret_cast<const short8*>((const char*)zh + abyte + akb);
            const short8 al = *reinterpret_cast<const short8*>((const char*)zl + abyte + akb);
            const int bb = ks * 8192 + bbase;
            const short8 bh  = *reinterpret_cast<const short8*>(&bsl[b][bb]);
            const short8 blo = *reinterpret_cast<const short8*>(&bsl[b][16384 + bb]);
            acc1 = __builtin_amdgcn_mfma_f32_32x32x16_bf16(ah, bh,  acc1, 0, 0, 0);
            acc2 = __builtin_amdgcn_mfma_f32_32x32x16_bf16(ah, blo, acc2, 0, 0, 0);
            acc2 = __builtin_amdgcn_mfma_f32_32x32x16_bf16(al, bh,  acc2, 0, 0, 0);
        }
        __builtin_amdgcn_s_setprio(0);
        __builtin_amdgcn_sched_barrier(0);
        asm volatile("s_barrier" ::: "memory");

        if (q == 7) {
            // ---- pass epilogue: dist + fold into running (b1, i1, b2) ----
            const int p = s >> 3;
            const int code = p * 256 + cg * 32 + l32;
            const float en = enorm_g[code];
#pragma unroll
            for (int reg = 0; reg < 16; ++reg) {
                const int rowl = (reg & 3) + ((reg >> 2) << 3) + (hi << 2);
                const float zr = znbuf[rg * 32 + rowl];
                const float dist = fmaf(-2.f, acc1[reg] + acc2[reg], zr + en);
                const float nb2 = fminf(stb2[reg], fmaxf(stb1[reg], dist));
                if (dist < stb1[reg]) { stb1[reg] = dist; sti1[reg] = code; }
                stb2[reg] = nb2;
            }
#pragma unroll
            for (int j = 0; j < 16; ++j) { acc1[j] = 0.f; acc2[j] = 0.f; }
        }
    }

    // ---- cross-lane reduce over 32 code lanes (offsets 1..16 keep hi-halves) ----
#pragma unroll
    for (int reg = 0; reg < 16; ++reg) {
#pragma unroll
        for (int o = 1; o < 32; o <<= 1) {
            const float ob1 = __shfl_xor(stb1[reg], o);
            const int   oi1 = __shfl_xor(sti1[reg], o);
            const float ob2 = __shfl_xor(stb2[reg], o);
            const float nb2 = fminf(fminf(stb2[reg], ob2), fmaxf(stb1[reg], ob1));
            if (ob1 < stb1[reg] || (ob1 == stb1[reg] && oi1 < sti1[reg])) {
                stb1[reg] = ob1; sti1[reg] = oi1;
            }
            stb2[reg] = nb2;
        }
    }
    if (l32 == 0) {
#pragma unroll
        for (int reg = 0; reg < 16; ++reg) {
            const int rowb = rg * 32 + (reg & 3) + ((reg >> 2) << 3) + (hi << 2);
            m_b1[cg][rowb] = stb1[reg];
            m_i1[cg][rowb] = sti1[reg];
            m_b2[cg][rowb] = stb2[reg];
        }
    }
    __syncthreads();
    if (t < 64) {
        float b1 = m_b1[0][t]; int i1 = m_i1[0][t]; float b2 = m_b2[0][t];
#pragma unroll
        for (int g = 1; g < 8; ++g) {
            const float ob1 = m_b1[g][t]; const int oi1 = m_i1[g][t]; const float ob2 = m_b2[g][t];
            const float nb2 = fminf(fminf(b2, ob2), fmaxf(b1, ob1));
            if (ob1 < b1 || (ob1 == b1 && oi1 < i1)) { b1 = ob1; i1 = oi1; }
            b2 = nb2;
        }
        const int grow = blockIdx.x * 64 + t;
        idx_out[grow] = (float)i1;
        if (b2 - b1 < THR_MARGIN) {
            const int pos = atomicAdd(wlcnt, 1);
            wl[pos] = grow;
        }
    }
}

// ---------------- kernel 2: exact fp32 fixup (worklist-driven) ----------------
__global__ __launch_bounds__(256)
void fixup_kernel(const float* __restrict__ z, const float* __restrict__ emb,
                  const float* __restrict__ enorm_g, const float* __restrict__ zn_g,
                  const int* __restrict__ wl, const int* __restrict__ wlcnt,
                  float* __restrict__ idx_out) {
    const int wid = blockIdx.x * 4 + (threadIdx.x >> 6);
    const int l = threadIdx.x & 63;
    int n = wlcnt[0];
    if (n > 65536) n = 65536;
#pragma unroll 1
    for (int i = wid; i < n; i += 4096) {
        const int r = wl[i];
        const float* zr = z + (size_t)r * 256;
        const float zn = zn_g[r];
        float b1 = 3.4e38f;
        int   i1 = 0;
#pragma unroll 1
        for (int tt = 0; tt < 16; ++tt) {
            const int c = l + tt * 64;           // ascending per lane
            const float* er = emb + (size_t)c * 256;
            float dot = 0.f;
#pragma unroll 4
            for (int d = 0; d < 256; d += 4) {
                const float4 zv = *reinterpret_cast<const float4*>(zr + d);
                const float4 ev = *reinterpret_cast<const float4*>(er + d);
                dot = fmaf(zv.x, ev.x, dot);
                dot = fmaf(zv.y, ev.y, dot);
                dot = fmaf(zv.z, ev.z, dot);
                dot = fmaf(zv.w, ev.w, dot);
            }
            const float dist = fmaf(-2.f, dot, zn + enorm_g[c]);
            if (dist < b1) { b1 = dist; i1 = c; }
        }
#pragma unroll
        for (int off = 1; off < 64; off <<= 1) {
            const float ov = __shfl_xor(b1, off);
            const int   oi = __shfl_xor(i1, off);
            if (ov < b1 || (ov == b1 && oi < i1)) { b1 = ov; i1 = oi; }
        }
        if (l == 0) idx_out[r] = (float)i1;
    }
}

// ---------------- kernel 3: gather + quantized output + loss partials ----------
__global__ __launch_bounds__(256)
void gather_kernel(const float* __restrict__ z, const float* __restrict__ emb,
                   const float* __restrict__ idx_f, float* __restrict__ q_out,
                   float* __restrict__ partials) {
    const int wv = threadIdx.x >> 6, ln = threadIdx.x & 63;
    float lsum = 0.f;
#pragma unroll
    for (int i = 0; i < 8; ++i) {
        const size_t row = (size_t)blockIdx.x * 32 + i * 4 + wv;
        const int kidx = (int)idx_f[row];
        const float4 e4 = *reinterpret_cast<const float4*>(emb + (size_t)kidx * 256 + ln * 4);
        const float4 z4 = *reinterpret_cast<const float4*>(z + row * 256 + ln * 4);
        *reinterpret_cast<float4*>(q_out + row * 256 + ln * 4) = e4;  // quantized_st == quantized
        const float dx = e4.x - z4.x, dy = e4.y - z4.y, dz = e4.z - z4.z, dw = e4.w - z4.w;
        lsum += dx * dx + dy * dy + dz * dz + dw * dw;
    }
#pragma unroll
    for (int off = 32; off > 0; off >>= 1) lsum += __shfl_xor(lsum, off);
    __shared__ float red[4];
    if (ln == 0) red[wv] = lsum;
    __syncthreads();
    if (threadIdx.x == 0) partials[blockIdx.x] = red[0] + red[1] + red[2] + red[3];
}

// ---------------- kernel 4: deterministic loss reduction ----------------------
__global__ __launch_bounds__(256)
void loss_kernel(const float* __restrict__ partials, float* __restrict__ loss_out) {
    const int tid = threadIdx.x;
    float s = 0.f;
#pragma unroll
    for (int i = 0; i < 8; ++i) s += partials[tid + i * 256];
#pragma unroll
    for (int off = 32; off > 0; off >>= 1) s += __shfl_xor(s, off);
    __shared__ float red[4];
    if ((tid & 63) == 0) red[tid >> 6] = s;
    __syncthreads();
    if (tid == 0)
        loss_out[0] = (red[0] + red[1] + red[2] + red[3]) * (1.25f / 16777216.0f);
}

extern "C" void kernel_launch(void* const* d_in, const int* in_sizes, int n_in,
                              void* d_out, int out_size, void* d_ws, size_t ws_size,
                              hipStream_t stream) {
    const float* z   = (const float*)d_in[0];
    const float* emb = (const float*)d_in[1];
    float* out      = (float*)d_out;
    float* q_out    = out;                       // 16,777,216 floats
    float* loss_out = out + 16777216;            // 1 float
    float* idx_out  = out + 16777217;            // 65,536 floats
    float* enorm    = (float*)d_ws;              // 1024 f32
    float* partials = (float*)d_ws + 1024;       // 2048 f32
    // scratch inside the q region (fully rewritten by gather afterwards):
    unsigned short* eh_g = (unsigned short*)q_out;          // 512 KB
    unsigned short* el_g = eh_g + 131072 * 2;               // 512 KB
    float* zn_g  = q_out + 262144;                          // 256 KB
    int*   wl    = (int*)(q_out + 327680);                  // 256 KB
    int*   wlcnt = (int*)(q_out + 393216);                  // 4 B

    eprep_kernel<<<1024, 256, 0, stream>>>(emb, eh_g, el_g, enorm, wlcnt);
    argmin_kernel<<<1024, 1024, 0, stream>>>(z, eh_g, el_g, enorm, idx_out, zn_g, wl, wlcnt);
    fixup_kernel<<<1024, 256, 0, stream>>>(z, emb, enorm, zn_g, wl, wlcnt, idx_out);
    gather_kernel<<<2048, 256, 0, stream>>>(z, emb, idx_out, q_out, partials);
    loss_kernel<<<1, 256, 0, stream>>>(partials, loss_out);
}

// Round 12
// 277.982 us; speedup vs baseline: 1.5014x; 1.5014x over previous
//
#include <hip/hip_runtime.h>
#include <stdint.h>

// VectorQuantizer — z:(16,256,64,64) f32 -> 65536 rows of 256; emb:(1024,256) f32.
// d_out: q[16777216] | vq_loss[1] | idx_as_float[65536]
//
// R12: operand-swapped MFMA argmin. A = codebook (pre-transposed [ks][code][hi][8],
// streamed global->reg, coalesced 1KB loads, 4-deep rotation); B = z (LDS-resident,
// swizzled, loaded once) -> ZERO barriers in main loop. D[code][zrow]: per-lane
// argmin state = 3 scalars. argmin needs no zn / no enorm (|e|^2 = 1 +- 1e-7;
// deviations << fixup threshold): track s = -dot, fixup recomputes exact dists.
// R11 lessons fixed: no launch-bounds spill (512,2), MFMA:LDS = 6:4KB per unit.

typedef __attribute__((ext_vector_type(8))) short short8;
typedef __attribute__((ext_vector_type(16))) float f32x16;

#define THR_S 1e-3f   // s-space margin threshold (= 2e-3 in dist space)

__device__ __forceinline__ unsigned short f2bf(float f) {
    const unsigned int x = __float_as_uint(f);
    return (unsigned short)((x + 0x7FFFu + ((x >> 16) & 1u)) >> 16);
}
__device__ __forceinline__ float bf2f(unsigned short h) {
    return __uint_as_float(((unsigned int)h) << 16);
}

#define MFMA32(A, B, C) __builtin_amdgcn_mfma_f32_32x32x16_bf16(A, B, C, 0, 0, 0)

// ---------------- kernel 0: e prep — transpose-split codebook + norms ----------
// eh_t/el_t layout: halfword idx = ks*16384 + code*16 + hi*8 + j   (ks=k>>4,
// hi=(k>>3)&1, j=k&7) -> a wave's 64-lane A-frag load is one contiguous 1 KB.
__global__ __launch_bounds__(256)
void eprep_kernel(const float* __restrict__ emb, unsigned short* __restrict__ eh_t,
                  unsigned short* __restrict__ el_t, float* __restrict__ enorm,
                  int* __restrict__ wlcnt) {
    const int code = blockIdx.x;
    const int k = threadIdx.x;
    if (code == 0 && k == 0) wlcnt[0] = 0;
    const float v = emb[code * 256 + k];
    const unsigned short h = f2bf(v);
    const int idx = ((k >> 4) << 14) + (code << 4) + (((k >> 3) & 1) << 3) + (k & 7);
    eh_t[idx] = h;
    el_t[idx] = f2bf(v - bf2f(h));
    float s = v * v;
#pragma unroll
    for (int o = 32; o > 0; o >>= 1) s += __shfl_xor(s, o);
    __shared__ float red[4];
    if ((k & 63) == 0) red[k >> 6] = s;
    __syncthreads();
    if (k == 0) enorm[code] = (red[0] + red[1]) + (red[2] + red[3]);
}

// ---------------- kernel 1: MFMA argmin (no-barrier main loop) ----------------
// 512 thr = 8 waves; block = 64 z-rows (2 rowtiles). Wave w owns codes
// w*128..w*128+127 (4 codetiles), iterated as 64 flat units (ct,ks).

#define UPD(S, C, B1, I1, B2) { \
    const bool lt_ = (S) < B1; \
    B2 = lt_ ? B1 : fminf(B2, (S)); \
    I1 = lt_ ? (C) : I1; \
    B1 = lt_ ? (S) : B1; }

#define MERGE32(B1, I1, B2) { \
    const float ob1_ = __shfl_xor(B1, 32); \
    const int   oi1_ = __shfl_xor(I1, 32); \
    const float ob2_ = __shfl_xor(B2, 32); \
    const float nb2_ = fminf(fminf(B2, ob2_), fmaxf(B1, ob1_)); \
    if (ob1_ < B1 || (ob1_ == B1 && oi1_ < I1)) { B1 = ob1_; I1 = oi1_; } \
    B2 = nb2_; }

#define PFLOAD(S, U) { \
    const int un_ = (U) & 63; \
    const int ofs_ = ((un_ & 15) << 15) + ((un_ >> 4) << 10); \
    pf##S##h = *reinterpret_cast<const short8*>(ehp + ofs_); \
    pf##S##l = *reinterpret_cast<const short8*>(elp + ofs_); }

#define UNIT(S, KS) { \
    const int ko_ = (((KS) << 5) + (hi << 4)) ^ rsw; \
    const short8 bh0 = *reinterpret_cast<const short8*>(zbuf + rb0 + ko_); \
    const short8 bl0 = *reinterpret_cast<const short8*>(zbuf + 32768 + rb0 + ko_); \
    const short8 bh1 = *reinterpret_cast<const short8*>(zbuf + rb1 + ko_); \
    const short8 bl1 = *reinterpret_cast<const short8*>(zbuf + 32768 + rb1 + ko_); \
    acc1a = MFMA32(pf##S##h, bh0, acc1a); \
    acc1b = MFMA32(pf##S##h, bh1, acc1b); \
    acc2a = MFMA32(pf##S##h, bl0, acc2a); \
    acc2b = MFMA32(pf##S##h, bl1, acc2b); \
    acc2a = MFMA32(pf##S##l, bh0, acc2a); \
    acc2b = MFMA32(pf##S##l, bh1, acc2b); }

__global__ __launch_bounds__(512, 2)
void argmin_kernel(const float* __restrict__ z, const unsigned short* __restrict__ eh_t,
                   float* __restrict__ idx_out, int* __restrict__ wl,
                   int* __restrict__ wlcnt) {
    __shared__ char zbuf[65536];          // zh 32K | zl 32K: byte = row*512 + (2k ^ ((row&7)<<4))
    __shared__ float m_b1[8][64];
    __shared__ int   m_i1[8][64];
    __shared__ float m_b2[8][64];

    const int t = threadIdx.x;
    const int l = t & 63;
    const int w = t >> 6;
    const int cl = l & 31;
    const int hi = l >> 5;

    const float* zblk = z + (size_t)blockIdx.x * 16384;

    // ---- stage z: fp32 -> bf16 hi/lo into swizzled LDS (once) ----
#pragma unroll
    for (int i = 0; i < 8; ++i) {
        const int idx = i * 2048 + t * 4;
        const int row = idx >> 8, k = idx & 255;
        const float4 v = *reinterpret_cast<const float4*>(zblk + idx);
        ushort4 hv, lv;
        hv.x = f2bf(v.x); lv.x = f2bf(v.x - bf2f(hv.x));
        hv.y = f2bf(v.y); lv.y = f2bf(v.y - bf2f(hv.y));
        hv.z = f2bf(v.z); lv.z = f2bf(v.z - bf2f(hv.z));
        hv.w = f2bf(v.w); lv.w = f2bf(v.w - bf2f(hv.w));
        const int boff = row * 512 + ((k << 1) ^ ((row & 7) << 4));
        *reinterpret_cast<ushort4*>(zbuf + boff) = hv;
        *reinterpret_cast<ushort4*>(zbuf + 32768 + boff) = lv;
    }
    __syncthreads();   // the ONLY barrier before the final merge

    // ---- A-stream pointers (coalesced: 64 lanes cover 1 KB contiguous) ----
    const char* ehp = (const char*)eh_t + (w * 128 + cl) * 32 + hi * 16;
    const char* elp = ehp + 524288;

    const int rb0 = cl * 512;           // rowtile 0: row = cl
    const int rb1 = rb0 + 16384;        // rowtile 1: row = cl + 32
    const int rsw = (cl & 7) << 4;      // same for cl and cl+32

    f32x16 acc1a, acc2a, acc1b, acc2b;
#pragma unroll
    for (int j = 0; j < 16; ++j) { acc1a[j] = 0.f; acc2a[j] = 0.f; acc1b[j] = 0.f; acc2b[j] = 0.f; }

    float b1a = 3.4e38f, b2a = 3.4e38f, b1b = 3.4e38f, b2b = 3.4e38f;
    int   i1a = 0, i1b = 0;

    short8 pf0h, pf0l, pf1h, pf1l, pf2h, pf2l, pf3h, pf3l;
    PFLOAD(0, 0) PFLOAD(1, 1) PFLOAD(2, 2) PFLOAD(3, 3)

#pragma unroll 1
    for (int ct = 0; ct < 4; ++ct) {
#pragma unroll 1
        for (int j = 0; j < 4; ++j) {
            const int u0 = (ct << 4) + (j << 2);
            UNIT(0, ((j << 2) + 0)) PFLOAD(0, u0 + 4)
            UNIT(1, ((j << 2) + 1)) PFLOAD(1, u0 + 5)
            UNIT(2, ((j << 2) + 2)) PFLOAD(2, u0 + 6)
            UNIT(3, ((j << 2) + 3)) PFLOAD(3, u0 + 7)
        }
        // ---- codetile epilogue: s = -dot, fold into (b1, i1, b2) ----
        const int code0 = w * 128 + (ct << 5) + (hi << 2);
#pragma unroll
        for (int reg = 0; reg < 16; ++reg) {
            const int code = code0 + (reg & 3) + ((reg >> 2) << 3);
            const float s0 = -(acc1a[reg] + acc2a[reg]);
            const float s1 = -(acc1b[reg] + acc2b[reg]);
            UPD(s0, code, b1a, i1a, b2a)
            UPD(s1, code, b1b, i1b, b2b)
            acc1a[reg] = 0.f; acc2a[reg] = 0.f; acc1b[reg] = 0.f; acc2b[reg] = 0.f;
        }
    }

    // ---- merge hi halves (lane ^ 32), then cross-wave via LDS ----
    MERGE32(b1a, i1a, b2a)
    MERGE32(b1b, i1b, b2b)
    if (l < 32) {
        m_b1[w][cl] = b1a;      m_i1[w][cl] = i1a;      m_b2[w][cl] = b2a;
        m_b1[w][cl + 32] = b1b; m_i1[w][cl + 32] = i1b; m_b2[w][cl + 32] = b2b;
    }
    __syncthreads();
    if (t < 64) {
        float b1 = m_b1[0][t]; int i1 = m_i1[0][t]; float b2 = m_b2[0][t];
#pragma unroll
        for (int g = 1; g < 8; ++g) {
            const float ob1 = m_b1[g][t]; const int oi1 = m_i1[g][t]; const float ob2 = m_b2[g][t];
            const float nb2 = fminf(fminf(b2, ob2), fmaxf(b1, ob1));
            if (ob1 < b1 || (ob1 == b1 && oi1 < i1)) { b1 = ob1; i1 = oi1; }
            b2 = nb2;
        }
        const int grow = blockIdx.x * 64 + t;
        idx_out[grow] = (float)i1;
        if (b2 - b1 < THR_S) {
            const int pos = atomicAdd(wlcnt, 1);
            wl[pos] = grow;
        }
    }
}

// ---------------- kernel 2: exact fp32 fixup (worklist-driven, self-zn) --------
__global__ __launch_bounds__(256)
void fixup_kernel(const float* __restrict__ z, const float* __restrict__ emb,
                  const float* __restrict__ enorm_g, const int* __restrict__ wl,
                  const int* __restrict__ wlcnt, float* __restrict__ idx_out) {
    const int wid = blockIdx.x * 4 + (threadIdx.x >> 6);
    const int l = threadIdx.x & 63;
    int n = wlcnt[0];
    if (n > 65536) n = 65536;
#pragma unroll 1
    for (int i = wid; i < n; i += 1024) {
        const int r = wl[i];
        const float* zr = z + (size_t)r * 256;
        const float4 v = *reinterpret_cast<const float4*>(zr + l * 4);
        float zn = fmaf(v.x, v.x, fmaf(v.y, v.y, fmaf(v.z, v.z, v.w * v.w)));
#pragma unroll
        for (int o = 32; o > 0; o >>= 1) zn += __shfl_xor(zn, o);
        float b1 = 3.4e38f;
        int   i1 = 0;
#pragma unroll 1
        for (int tt = 0; tt < 16; ++tt) {
            const int c = l + tt * 64;           // ascending per lane
            const float* er = emb + (size_t)c * 256;
            float dot = 0.f;
#pragma unroll 4
            for (int d = 0; d < 256; d += 4) {
                const float4 zv = *reinterpret_cast<const float4*>(zr + d);
                const float4 ev = *reinterpret_cast<const float4*>(er + d);
                dot = fmaf(zv.x, ev.x, dot);
                dot = fmaf(zv.y, ev.y, dot);
                dot = fmaf(zv.z, ev.z, dot);
                dot = fmaf(zv.w, ev.w, dot);
            }
            const float dist = fmaf(-2.f, dot, zn + enorm_g[c]);
            if (dist < b1) { b1 = dist; i1 = c; }
        }
#pragma unroll
        for (int off = 1; off < 64; off <<= 1) {
            const float ov = __shfl_xor(b1, off);
            const int   oi = __shfl_xor(i1, off);
            if (ov < b1 || (ov == b1 && oi < i1)) { b1 = ov; i1 = oi; }
        }
        if (l == 0) idx_out[r] = (float)i1;
    }
}

// ---------------- kernel 3: gather + quantized output + loss partials ----------
__global__ __launch_bounds__(256)
void gather_kernel(const float* __restrict__ z, const float* __restrict__ emb,
                   const float* __restrict__ idx_f, float* __restrict__ q_out,
                   float* __restrict__ partials) {
    const int wv = threadIdx.x >> 6, ln = threadIdx.x & 63;
    float lsum = 0.f;
#pragma unroll
    for (int i = 0; i < 8; ++i) {
        const size_t row = (size_t)blockIdx.x * 32 + i * 4 + wv;
        const int kidx = (int)idx_f[row];
        const float4 e4 = *reinterpret_cast<const float4*>(emb + (size_t)kidx * 256 + ln * 4);
        const float4 z4 = *reinterpret_cast<const float4*>(z + row * 256 + ln * 4);
        *reinterpret_cast<float4*>(q_out + row * 256 + ln * 4) = e4;  // quantized_st == quantized
        const float dx = e4.x - z4.x, dy = e4.y - z4.y, dz = e4.z - z4.z, dw = e4.w - z4.w;
        lsum += dx * dx + dy * dy + dz * dz + dw * dw;
    }
#pragma unroll
    for (int off = 32; off > 0; off >>= 1) lsum += __shfl_xor(lsum, off);
    __shared__ float red[4];
    if (ln == 0) red[wv] = lsum;
    __syncthreads();
    if (threadIdx.x == 0) partials[blockIdx.x] = red[0] + red[1] + red[2] + red[3];
}

// ---------------- kernel 4: deterministic loss reduction ----------------------
__global__ __launch_bounds__(256)
void loss_kernel(const float* __restrict__ partials, float* __restrict__ loss_out) {
    const int tid = threadIdx.x;
    float s = 0.f;
#pragma unroll
    for (int i = 0; i < 8; ++i) s += partials[tid + i * 256];
#pragma unroll
    for (int off = 32; off > 0; off >>= 1) s += __shfl_xor(s, off);
    __shared__ float red[4];
    if ((tid & 63) == 0) red[tid >> 6] = s;
    __syncthreads();
    if (tid == 0)
        loss_out[0] = (red[0] + red[1] + red[2] + red[3]) * (1.25f / 16777216.0f);
}

extern "C" void kernel_launch(void* const* d_in, const int* in_sizes, int n_in,
                              void* d_out, int out_size, void* d_ws, size_t ws_size,
                              hipStream_t stream) {
    const float* z   = (const float*)d_in[0];
    const float* emb = (const float*)d_in[1];
    float* out      = (float*)d_out;
    float* q_out    = out;                       // 16,777,216 floats
    float* loss_out = out + 16777216;            // 1 float
    float* idx_out  = out + 16777217;            // 65,536 floats
    float* enorm    = (float*)d_ws;              // 1024 f32
    float* partials = (float*)d_ws + 1024;       // 2048 f32
    // scratch inside the q region (fully rewritten by gather afterwards):
    unsigned short* eh_t = (unsigned short*)q_out;          // 512 KB  [ks][code][hi][8]
    unsigned short* el_t = eh_t + 262144;                   // 512 KB (float ofs 131072)
    int*   wl    = (int*)(q_out + 262144);                  // 256 KB
    int*   wlcnt = (int*)(q_out + 327680);                  // 4 B

    eprep_kernel<<<1024, 256, 0, stream>>>(emb, eh_t, el_t, enorm, wlcnt);
    argmin_kernel<<<1024, 512, 0, stream>>>(z, eh_t, idx_out, wl, wlcnt);
    fixup_kernel<<<256, 256, 0, stream>>>(z, emb, enorm, wl, wlcnt, idx_out);
    gather_kernel<<<2048, 256, 0, stream>>>(z, emb, idx_out, q_out, partials);
    loss_kernel<<<1, 256, 0, stream>>>(partials, loss_out);
}

// Round 13
// 174.941 us; speedup vs baseline: 2.3857x; 1.5890x over previous
//
#include <hip/hip_runtime.h>
#include <stdint.h>

// VectorQuantizer — z:(16,256,64,64) f32 -> 65536 rows of 256; emb:(1024,256) f32.
// d_out: q[16777216] | vq_loss[1] | idx_as_float[65536]
//
// R13 = R12 (operand-swapped MFMA argmin, no-barrier main loop) + latency-fixed
// fixup: R12's fixup was ~146us because each worklist row was ONE wave doing
// per-lane scattered emb-row walks + a 256-deep dependent fma chain (dur =
// per-row LATENCY). Now: one block per row, dq-quad coalesced loads, quad
// shuffle combine -> ~2us/row, rows parallel across blocks.

typedef __attribute__((ext_vector_type(8))) short short8;
typedef __attribute__((ext_vector_type(16))) float f32x16;

#define THR_S 1e-3f   // s-space margin threshold (= 2e-3 in dist space)

__device__ __forceinline__ unsigned short f2bf(float f) {
    const unsigned int x = __float_as_uint(f);
    return (unsigned short)((x + 0x7FFFu + ((x >> 16) & 1u)) >> 16);
}
__device__ __forceinline__ float bf2f(unsigned short h) {
    return __uint_as_float(((unsigned int)h) << 16);
}

#define MFMA32(A, B, C) __builtin_amdgcn_mfma_f32_32x32x16_bf16(A, B, C, 0, 0, 0)

// ---------------- kernel 0: e prep — transpose-split codebook + norms ----------
__global__ __launch_bounds__(256)
void eprep_kernel(const float* __restrict__ emb, unsigned short* __restrict__ eh_t,
                  unsigned short* __restrict__ el_t, float* __restrict__ enorm,
                  int* __restrict__ wlcnt) {
    const int code = blockIdx.x;
    const int k = threadIdx.x;
    if (code == 0 && k == 0) wlcnt[0] = 0;
    const float v = emb[code * 256 + k];
    const unsigned short h = f2bf(v);
    const int idx = ((k >> 4) << 14) + (code << 4) + (((k >> 3) & 1) << 3) + (k & 7);
    eh_t[idx] = h;
    el_t[idx] = f2bf(v - bf2f(h));
    float s = v * v;
#pragma unroll
    for (int o = 32; o > 0; o >>= 1) s += __shfl_xor(s, o);
    __shared__ float red[4];
    if ((k & 63) == 0) red[k >> 6] = s;
    __syncthreads();
    if (k == 0) enorm[code] = (red[0] + red[1]) + (red[2] + red[3]);
}

// ---------------- kernel 1: MFMA argmin (no-barrier main loop) — as R12 -------
#define UPD(S, C, B1, I1, B2) { \
    const bool lt_ = (S) < B1; \
    B2 = lt_ ? B1 : fminf(B2, (S)); \
    I1 = lt_ ? (C) : I1; \
    B1 = lt_ ? (S) : B1; }

#define MERGE32(B1, I1, B2) { \
    const float ob1_ = __shfl_xor(B1, 32); \
    const int   oi1_ = __shfl_xor(I1, 32); \
    const float ob2_ = __shfl_xor(B2, 32); \
    const float nb2_ = fminf(fminf(B2, ob2_), fmaxf(B1, ob1_)); \
    if (ob1_ < B1 || (ob1_ == B1 && oi1_ < I1)) { B1 = ob1_; I1 = oi1_; } \
    B2 = nb2_; }

#define PFLOAD(S, U) { \
    const int un_ = (U) & 63; \
    const int ofs_ = ((un_ & 15) << 15) + ((un_ >> 4) << 10); \
    pf##S##h = *reinterpret_cast<const short8*>(ehp + ofs_); \
    pf##S##l = *reinterpret_cast<const short8*>(elp + ofs_); }

#define UNIT(S, KS) { \
    const int ko_ = (((KS) << 5) + (hi << 4)) ^ rsw; \
    const short8 bh0 = *reinterpret_cast<const short8*>(zbuf + rb0 + ko_); \
    const short8 bl0 = *reinterpret_cast<const short8*>(zbuf + 32768 + rb0 + ko_); \
    const short8 bh1 = *reinterpret_cast<const short8*>(zbuf + rb1 + ko_); \
    const short8 bl1 = *reinterpret_cast<const short8*>(zbuf + 32768 + rb1 + ko_); \
    acc1a = MFMA32(pf##S##h, bh0, acc1a); \
    acc1b = MFMA32(pf##S##h, bh1, acc1b); \
    acc2a = MFMA32(pf##S##h, bl0, acc2a); \
    acc2b = MFMA32(pf##S##h, bl1, acc2b); \
    acc2a = MFMA32(pf##S##l, bh0, acc2a); \
    acc2b = MFMA32(pf##S##l, bh1, acc2b); }

__global__ __launch_bounds__(512, 2)
void argmin_kernel(const float* __restrict__ z, const unsigned short* __restrict__ eh_t,
                   float* __restrict__ idx_out, int* __restrict__ wl,
                   int* __restrict__ wlcnt) {
    __shared__ char zbuf[65536];          // zh 32K | zl 32K: byte = row*512 + (2k ^ ((row&7)<<4))
    __shared__ float m_b1[8][64];
    __shared__ int   m_i1[8][64];
    __shared__ float m_b2[8][64];

    const int t = threadIdx.x;
    const int l = t & 63;
    const int w = t >> 6;
    const int cl = l & 31;
    const int hi = l >> 5;

    const float* zblk = z + (size_t)blockIdx.x * 16384;

    // ---- stage z: fp32 -> bf16 hi/lo into swizzled LDS (once) ----
#pragma unroll
    for (int i = 0; i < 8; ++i) {
        const int idx = i * 2048 + t * 4;
        const int row = idx >> 8, k = idx & 255;
        const float4 v = *reinterpret_cast<const float4*>(zblk + idx);
        ushort4 hv, lv;
        hv.x = f2bf(v.x); lv.x = f2bf(v.x - bf2f(hv.x));
        hv.y = f2bf(v.y); lv.y = f2bf(v.y - bf2f(hv.y));
        hv.z = f2bf(v.z); lv.z = f2bf(v.z - bf2f(hv.z));
        hv.w = f2bf(v.w); lv.w = f2bf(v.w - bf2f(hv.w));
        const int boff = row * 512 + ((k << 1) ^ ((row & 7) << 4));
        *reinterpret_cast<ushort4*>(zbuf + boff) = hv;
        *reinterpret_cast<ushort4*>(zbuf + 32768 + boff) = lv;
    }
    __syncthreads();   // the ONLY barrier before the final merge

    const char* ehp = (const char*)eh_t + (w * 128 + cl) * 32 + hi * 16;
    const char* elp = ehp + 524288;

    const int rb0 = cl * 512;
    const int rb1 = rb0 + 16384;
    const int rsw = (cl & 7) << 4;

    f32x16 acc1a, acc2a, acc1b, acc2b;
#pragma unroll
    for (int j = 0; j < 16; ++j) { acc1a[j] = 0.f; acc2a[j] = 0.f; acc1b[j] = 0.f; acc2b[j] = 0.f; }

    float b1a = 3.4e38f, b2a = 3.4e38f, b1b = 3.4e38f, b2b = 3.4e38f;
    int   i1a = 0, i1b = 0;

    short8 pf0h, pf0l, pf1h, pf1l, pf2h, pf2l, pf3h, pf3l;
    PFLOAD(0, 0) PFLOAD(1, 1) PFLOAD(2, 2) PFLOAD(3, 3)

#pragma unroll 1
    for (int ct = 0; ct < 4; ++ct) {
#pragma unroll 1
        for (int j = 0; j < 4; ++j) {
            const int u0 = (ct << 4) + (j << 2);
            UNIT(0, ((j << 2) + 0)) PFLOAD(0, u0 + 4)
            UNIT(1, ((j << 2) + 1)) PFLOAD(1, u0 + 5)
            UNIT(2, ((j << 2) + 2)) PFLOAD(2, u0 + 6)
            UNIT(3, ((j << 2) + 3)) PFLOAD(3, u0 + 7)
        }
        const int code0 = w * 128 + (ct << 5) + (hi << 2);
#pragma unroll
        for (int reg = 0; reg < 16; ++reg) {
            const int code = code0 + (reg & 3) + ((reg >> 2) << 3);
            const float s0 = -(acc1a[reg] + acc2a[reg]);
            const float s1 = -(acc1b[reg] + acc2b[reg]);
            UPD(s0, code, b1a, i1a, b2a)
            UPD(s1, code, b1b, i1b, b2b)
            acc1a[reg] = 0.f; acc2a[reg] = 0.f; acc1b[reg] = 0.f; acc2b[reg] = 0.f;
        }
    }

    MERGE32(b1a, i1a, b2a)
    MERGE32(b1b, i1b, b2b)
    if (l < 32) {
        m_b1[w][cl] = b1a;      m_i1[w][cl] = i1a;      m_b2[w][cl] = b2a;
        m_b1[w][cl + 32] = b1b; m_i1[w][cl + 32] = i1b; m_b2[w][cl + 32] = b2b;
    }
    __syncthreads();
    if (t < 64) {
        float b1 = m_b1[0][t]; int i1 = m_i1[0][t]; float b2 = m_b2[0][t];
#pragma unroll
        for (int g = 1; g < 8; ++g) {
            const float ob1 = m_b1[g][t]; const int oi1 = m_i1[g][t]; const float ob2 = m_b2[g][t];
            const float nb2 = fminf(fminf(b2, ob2), fmaxf(b1, ob1));
            if (ob1 < b1 || (ob1 == b1 && oi1 < i1)) { b1 = ob1; i1 = oi1; }
            b2 = nb2;
        }
        const int grow = blockIdx.x * 64 + t;
        idx_out[grow] = (float)i1;
        if (b2 - b1 < THR_S) {
            const int pos = atomicAdd(wlcnt, 1);
            wl[pos] = grow;
        }
    }
}

// ---------------- kernel 2: exact fp32 fixup — block-per-row, dq-quad ---------
// One block (256 thr) per worklist row. Lane (dq=l&3, tx=(l>>2)&15); wave wv
// owns codes wv*256 + cc*16 + tx (cc=0..15); dq-quads read contiguous 64B
// lines of emb; quad __shfl_xor(1,2) combines quarter-dots. Exact fp32.
__global__ __launch_bounds__(256)
void fixup_kernel(const float* __restrict__ z, const float* __restrict__ emb,
                  const float* __restrict__ enorm_g, const int* __restrict__ wl,
                  const int* __restrict__ wlcnt, float* __restrict__ idx_out) {
    __shared__ float zrow[256];
    __shared__ float znred[4];
    __shared__ float mb[4];
    __shared__ int   mi[4];

    const int t = threadIdx.x;
    const int l = t & 63, wv = t >> 6;
    const int dq = l & 3, tx = (l >> 2) & 15;

    int n = wlcnt[0];
    if (n > 65536) n = 65536;

#pragma unroll 1
    for (int i = blockIdx.x; i < n; i += 256) {
        const int r = wl[i];
        // ---- stage z row + zn ----
        const float v = z[(size_t)r * 256 + t];
        zrow[t] = v;
        float zn = v * v;
#pragma unroll
        for (int o = 32; o > 0; o >>= 1) zn += __shfl_xor(zn, o);
        if (l == 0) znred[wv] = zn;
        __syncthreads();
        const float znf = (znred[0] + znred[1]) + (znred[2] + znred[3]);

        float b1 = 3.4e38f;
        int   i1 = 0;
#pragma unroll 1
        for (int cc = 0; cc < 16; ++cc) {
            const int c = wv * 256 + cc * 16 + tx;    // ascending per lane slot
            const float* er = emb + (size_t)c * 256 + dq * 4;
            float dot = 0.f;
#pragma unroll
            for (int j = 0; j < 16; ++j) {            // quarter: dims j*16 + dq*4 .. +3
                const float4 ev = *reinterpret_cast<const float4*>(er + j * 16);
                const float4 zv = *reinterpret_cast<const float4*>(&zrow[j * 16 + dq * 4]);
                dot = fmaf(zv.x, ev.x, dot);
                dot = fmaf(zv.y, ev.y, dot);
                dot = fmaf(zv.z, ev.z, dot);
                dot = fmaf(zv.w, ev.w, dot);
            }
            dot += __shfl_xor(dot, 1);                // combine dq quarters
            dot += __shfl_xor(dot, 2);
            const float dist = fmaf(-2.f, dot, znf + enorm_g[c]);
            if (dist < b1) { b1 = dist; i1 = c; }
        }
        // ---- reduce across tx lanes (bits 2..5); dq lanes are duplicates ----
#pragma unroll
        for (int off = 4; off < 64; off <<= 1) {
            const float ov = __shfl_xor(b1, off);
            const int   oi = __shfl_xor(i1, off);
            if (ov < b1 || (ov == b1 && oi < i1)) { b1 = ov; i1 = oi; }
        }
        if (l == 0) { mb[wv] = b1; mi[wv] = i1; }
        __syncthreads();
        if (t == 0) {
            float fb = mb[0]; int fi = mi[0];
#pragma unroll
            for (int g = 1; g < 4; ++g)
                if (mb[g] < fb || (mb[g] == fb && mi[g] < fi)) { fb = mb[g]; fi = mi[g]; }
            idx_out[r] = (float)fi;
        }
        __syncthreads();   // zrow/znred/mb reused next iteration
    }
}

// ---------------- kernel 3: gather + quantized output + loss partials ----------
__global__ __launch_bounds__(256)
void gather_kernel(const float* __restrict__ z, const float* __restrict__ emb,
                   const float* __restrict__ idx_f, float* __restrict__ q_out,
                   float* __restrict__ partials) {
    const int wv = threadIdx.x >> 6, ln = threadIdx.x & 63;
    float lsum = 0.f;
#pragma unroll
    for (int i = 0; i < 8; ++i) {
        const size_t row = (size_t)blockIdx.x * 32 + i * 4 + wv;
        const int kidx = (int)idx_f[row];
        const float4 e4 = *reinterpret_cast<const float4*>(emb + (size_t)kidx * 256 + ln * 4);
        const float4 z4 = *reinterpret_cast<const float4*>(z + row * 256 + ln * 4);
        *reinterpret_cast<float4*>(q_out + row * 256 + ln * 4) = e4;  // quantized_st == quantized
        const float dx = e4.x - z4.x, dy = e4.y - z4.y, dz = e4.z - z4.z, dw = e4.w - z4.w;
        lsum += dx * dx + dy * dy + dz * dz + dw * dw;
    }
#pragma unroll
    for (int off = 32; off > 0; off >>= 1) lsum += __shfl_xor(lsum, off);
    __shared__ float red[4];
    if (ln == 0) red[wv] = lsum;
    __syncthreads();
    if (threadIdx.x == 0) partials[blockIdx.x] = red[0] + red[1] + red[2] + red[3];
}

// ---------------- kernel 4: deterministic loss reduction ----------------------
__global__ __launch_bounds__(256)
void loss_kernel(const float* __restrict__ partials, float* __restrict__ loss_out) {
    const int tid = threadIdx.x;
    float s = 0.f;
#pragma unroll
    for (int i = 0; i < 8; ++i) s += partials[tid + i * 256];
#pragma unroll
    for (int off = 32; off > 0; off >>= 1) s += __shfl_xor(s, off);
    __shared__ float red[4];
    if ((tid & 63) == 0) red[tid >> 6] = s;
    __syncthreads();
    if (tid == 0)
        loss_out[0] = (red[0] + red[1] + red[2] + red[3]) * (1.25f / 16777216.0f);
}

extern "C" void kernel_launch(void* const* d_in, const int* in_sizes, int n_in,
                              void* d_out, int out_size, void* d_ws, size_t ws_size,
                              hipStream_t stream) {
    const float* z   = (const float*)d_in[0];
    const float* emb = (const float*)d_in[1];
    float* out      = (float*)d_out;
    float* q_out    = out;                       // 16,777,216 floats
    float* loss_out = out + 16777216;            // 1 float
    float* idx_out  = out + 16777217;            // 65,536 floats
    float* enorm    = (float*)d_ws;              // 1024 f32
    float* partials = (float*)d_ws + 1024;       // 2048 f32
    // scratch inside the q region (fully rewritten by gather afterwards):
    unsigned short* eh_t = (unsigned short*)q_out;          // 512 KB  [ks][code][hi][8]
    unsigned short* el_t = eh_t + 262144;                   // 512 KB (float ofs 131072)
    int*   wl    = (int*)(q_out + 262144);                  // 256 KB
    int*   wlcnt = (int*)(q_out + 327680);                  // 4 B

    eprep_kernel<<<1024, 256, 0, stream>>>(emb, eh_t, el_t, enorm, wlcnt);
    argmin_kernel<<<1024, 512, 0, stream>>>(z, eh_t, idx_out, wl, wlcnt);
    fixup_kernel<<<256, 256, 0, stream>>>(z, emb, enorm, wl, wlcnt, idx_out);
    gather_kernel<<<2048, 256, 0, stream>>>(z, emb, idx_out, q_out, partials);
    loss_kernel<<<1, 256, 0, stream>>>(partials, loss_out);
}

// Round 14
// 162.892 us; speedup vs baseline: 2.5622x; 1.0740x over previous
//
#include <hip/hip_runtime.h>
#include <stdint.h>

// VectorQuantizer — z:(16,256,64,64) f32 -> 65536 rows of 256; emb:(1024,256) f32.
// d_out: q[16777216] | vq_loss[1] | idx_as_float[65536]
//
// R14 = R13 + (a) gather/loss fused into argmin epilogue (z already in LDS as
// bf16 hi/lo; reconstruction error ~1e-5 << loss tolerance; saves 64MB z
// re-read + a launch), (b) 8-deep A-prefetch rotation (384cyc L2 cover vs
// R13's marginal 192), (c) fixup patches q + emits loss deltas; loss adds them.
// Scratch in d_ws (1.2MB) since argmin now writes q; host fallback to the
// R13 5-kernel flow if ws_size is too small.

typedef __attribute__((ext_vector_type(8))) short short8;
typedef __attribute__((ext_vector_type(16))) float f32x16;

#define THR_S 1e-3f     // s-space margin threshold (= 2e-3 in dist space)
#define WLCAP 16384

__device__ __forceinline__ unsigned short f2bf(float f) {
    const unsigned int x = __float_as_uint(f);
    return (unsigned short)((x + 0x7FFFu + ((x >> 16) & 1u)) >> 16);
}
__device__ __forceinline__ float bf2f(unsigned short h) {
    return __uint_as_float(((unsigned int)h) << 16);
}

#define MFMA32(A, B, C) __builtin_amdgcn_mfma_f32_32x32x16_bf16(A, B, C, 0, 0, 0)

// ---------------- kernel 0: e prep — transpose-split codebook + norms ----------
__global__ __launch_bounds__(256)
void eprep_kernel(const float* __restrict__ emb, unsigned short* __restrict__ eh_t,
                  unsigned short* __restrict__ el_t, float* __restrict__ enorm,
                  int* __restrict__ wlcnt) {
    const int code = blockIdx.x;
    const int k = threadIdx.x;
    if (code == 0 && k == 0) wlcnt[0] = 0;
    const float v = emb[code * 256 + k];
    const unsigned short h = f2bf(v);
    const int idx = ((k >> 4) << 14) + (code << 4) + (((k >> 3) & 1) << 3) + (k & 7);
    eh_t[idx] = h;
    el_t[idx] = f2bf(v - bf2f(h));
    float s = v * v;
#pragma unroll
    for (int o = 32; o > 0; o >>= 1) s += __shfl_xor(s, o);
    __shared__ float red[4];
    if ((k & 63) == 0) red[k >> 6] = s;
    __syncthreads();
    if (k == 0) enorm[code] = (red[0] + red[1]) + (red[2] + red[3]);
}

// ---------------- kernel 1: MFMA argmin + fused gather/loss ----------------
#define UPD(S, C, B1, I1, B2) { \
    const bool lt_ = (S) < B1; \
    B2 = lt_ ? B1 : fminf(B2, (S)); \
    I1 = lt_ ? (C) : I1; \
    B1 = lt_ ? (S) : B1; }

#define MERGE32(B1, I1, B2) { \
    const float ob1_ = __shfl_xor(B1, 32); \
    const int   oi1_ = __shfl_xor(I1, 32); \
    const float ob2_ = __shfl_xor(B2, 32); \
    const float nb2_ = fminf(fminf(B2, ob2_), fmaxf(B1, ob1_)); \
    if (ob1_ < B1 || (ob1_ == B1 && oi1_ < I1)) { B1 = ob1_; I1 = oi1_; } \
    B2 = nb2_; }

#define PFLOAD(S, U) { \
    const int un_ = (U) & 63; \
    const int ofs_ = ((un_ & 15) << 15) + ((un_ >> 4) << 10); \
    pf##S##h = *reinterpret_cast<const short8*>(ehp + ofs_); \
    pf##S##l = *reinterpret_cast<const short8*>(elp + ofs_); }

#define UNIT(S, KS) { \
    const int ko_ = (((KS) << 5) + (hi << 4)) ^ rsw; \
    const short8 bh0 = *reinterpret_cast<const short8*>(zbuf + rb0 + ko_); \
    const short8 bl0 = *reinterpret_cast<const short8*>(zbuf + 32768 + rb0 + ko_); \
    const short8 bh1 = *reinterpret_cast<const short8*>(zbuf + rb1 + ko_); \
    const short8 bl1 = *reinterpret_cast<const short8*>(zbuf + 32768 + rb1 + ko_); \
    acc1a = MFMA32(pf##S##h, bh0, acc1a); \
    acc1b = MFMA32(pf##S##h, bh1, acc1b); \
    acc2a = MFMA32(pf##S##h, bl0, acc2a); \
    acc2b = MFMA32(pf##S##h, bl1, acc2b); \
    acc2a = MFMA32(pf##S##l, bh0, acc2a); \
    acc2b = MFMA32(pf##S##l, bh1, acc2b); }

__global__ __launch_bounds__(512, 2)
void argmin_kernel(const float* __restrict__ z, const unsigned short* __restrict__ eh_t,
                   float* __restrict__ idx_out, int* __restrict__ wl,
                   int* __restrict__ wlcnt, const float* __restrict__ emb,
                   float* __restrict__ q_out, float* __restrict__ partials) {
    __shared__ char zbuf[65536];          // zh 32K | zl 32K: byte = row*512 + (2k ^ ((row&7)<<4))
    __shared__ float m_b1[8][64];
    __shared__ int   m_i1[8][64];
    __shared__ float m_b2[8][64];
    __shared__ int   fidx_s[64];

    const int t = threadIdx.x;
    const int l = t & 63;
    const int w = t >> 6;
    const int cl = l & 31;
    const int hi = l >> 5;

    const float* zblk = z + (size_t)blockIdx.x * 16384;

    // ---- stage z: fp32 -> bf16 hi/lo into swizzled LDS (once) ----
#pragma unroll
    for (int i = 0; i < 8; ++i) {
        const int idx = i * 2048 + t * 4;
        const int row = idx >> 8, k = idx & 255;
        const float4 v = *reinterpret_cast<const float4*>(zblk + idx);
        ushort4 hv, lv;
        hv.x = f2bf(v.x); lv.x = f2bf(v.x - bf2f(hv.x));
        hv.y = f2bf(v.y); lv.y = f2bf(v.y - bf2f(hv.y));
        hv.z = f2bf(v.z); lv.z = f2bf(v.z - bf2f(hv.z));
        hv.w = f2bf(v.w); lv.w = f2bf(v.w - bf2f(hv.w));
        const int boff = row * 512 + ((k << 1) ^ ((row & 7) << 4));
        *reinterpret_cast<ushort4*>(zbuf + boff) = hv;
        *reinterpret_cast<ushort4*>(zbuf + 32768 + boff) = lv;
    }
    __syncthreads();

    const char* ehp = (const char*)eh_t + (w * 128 + cl) * 32 + hi * 16;
    const char* elp = ehp + 524288;

    const int rb0 = cl * 512;
    const int rb1 = rb0 + 16384;
    const int rsw = (cl & 7) << 4;

    f32x16 acc1a, acc2a, acc1b, acc2b;
#pragma unroll
    for (int j = 0; j < 16; ++j) { acc1a[j] = 0.f; acc2a[j] = 0.f; acc1b[j] = 0.f; acc2b[j] = 0.f; }

    float b1a = 3.4e38f, b2a = 3.4e38f, b1b = 3.4e38f, b2b = 3.4e38f;
    int   i1a = 0, i1b = 0;

    short8 pf0h, pf0l, pf1h, pf1l, pf2h, pf2l, pf3h, pf3l;
    short8 pf4h, pf4l, pf5h, pf5l, pf6h, pf6l, pf7h, pf7l;
    PFLOAD(0, 0) PFLOAD(1, 1) PFLOAD(2, 2) PFLOAD(3, 3)
    PFLOAD(4, 4) PFLOAD(5, 5) PFLOAD(6, 6) PFLOAD(7, 7)

#pragma unroll 1
    for (int ct = 0; ct < 4; ++ct) {
#pragma unroll 1
        for (int hh = 0; hh < 2; ++hh) {
            const int u0 = (ct << 4) + (hh << 3);
            const int k0 = hh << 3;
            UNIT(0, k0 + 0) PFLOAD(0, u0 + 8)
            UNIT(1, k0 + 1) PFLOAD(1, u0 + 9)
            UNIT(2, k0 + 2) PFLOAD(2, u0 + 10)
            UNIT(3, k0 + 3) PFLOAD(3, u0 + 11)
            UNIT(4, k0 + 4) PFLOAD(4, u0 + 12)
            UNIT(5, k0 + 5) PFLOAD(5, u0 + 13)
            UNIT(6, k0 + 6) PFLOAD(6, u0 + 14)
            UNIT(7, k0 + 7) PFLOAD(7, u0 + 15)
        }
        const int code0 = w * 128 + (ct << 5) + (hi << 2);
#pragma unroll
        for (int reg = 0; reg < 16; ++reg) {
            const int code = code0 + (reg & 3) + ((reg >> 2) << 3);
            const float s0 = -(acc1a[reg] + acc2a[reg]);
            const float s1 = -(acc1b[reg] + acc2b[reg]);
            UPD(s0, code, b1a, i1a, b2a)
            UPD(s1, code, b1b, i1b, b2b)
            acc1a[reg] = 0.f; acc2a[reg] = 0.f; acc1b[reg] = 0.f; acc2b[reg] = 0.f;
        }
    }

    MERGE32(b1a, i1a, b2a)
    MERGE32(b1b, i1b, b2b)
    if (l < 32) {
        m_b1[w][cl] = b1a;      m_i1[w][cl] = i1a;      m_b2[w][cl] = b2a;
        m_b1[w][cl + 32] = b1b; m_i1[w][cl + 32] = i1b; m_b2[w][cl + 32] = b2b;
    }
    __syncthreads();
    if (t < 64) {
        float b1 = m_b1[0][t]; int i1 = m_i1[0][t]; float b2 = m_b2[0][t];
#pragma unroll
        for (int g = 1; g < 8; ++g) {
            const float ob1 = m_b1[g][t]; const int oi1 = m_i1[g][t]; const float ob2 = m_b2[g][t];
            const float nb2 = fminf(fminf(b2, ob2), fmaxf(b1, ob1));
            if (ob1 < b1 || (ob1 == b1 && oi1 < i1)) { b1 = ob1; i1 = oi1; }
            b2 = nb2;
        }
        const int grow = blockIdx.x * 64 + t;
        idx_out[grow] = (float)i1;
        fidx_s[t] = i1;
        if (b2 - b1 < THR_S) {
            const int pos = atomicAdd(wlcnt, 1);
            if (pos < WLCAP) wl[pos] = grow;
        }
    }

    // ---- fused gather + loss partial (skipped in fallback mode) ----
    if (q_out != nullptr) {
        __syncthreads();   // fidx_s visible
        float lsum = 0.f;
        float* qblk = q_out + (size_t)blockIdx.x * 16384;
#pragma unroll
        for (int i = 0; i < 8; ++i) {
            const int row = i * 8 + w;     // wave w handles row i*8+w (uniform)
            const int code = fidx_s[row];
            const float4 e4 = *reinterpret_cast<const float4*>(
                emb + (size_t)code * 256 + l * 4);
            const int byt = row * 512 + ((l * 8) ^ ((row & 7) << 4));
            const ushort4 h4 = *reinterpret_cast<const ushort4*>(zbuf + byt);
            const ushort4 l4 = *reinterpret_cast<const ushort4*>(zbuf + 32768 + byt);
            const float zx = bf2f(h4.x) + bf2f(l4.x);
            const float zy = bf2f(h4.y) + bf2f(l4.y);
            const float zz = bf2f(h4.z) + bf2f(l4.z);
            const float zw = bf2f(h4.w) + bf2f(l4.w);
            const float dx = e4.x - zx, dy = e4.y - zy, dz = e4.z - zz, dw = e4.w - zw;
            lsum += dx * dx + dy * dy + dz * dz + dw * dw;
            *reinterpret_cast<float4*>(qblk + row * 256 + l * 4) = e4;
        }
#pragma unroll
        for (int o = 32; o > 0; o >>= 1) lsum += __shfl_xor(lsum, o);
        if (l == 0) m_b1[0][w] = lsum;    // reuse merge LDS as scratch
        __syncthreads();
        if (t == 0) {
            float s = 0.f;
#pragma unroll
            for (int g = 0; g < 8; ++g) s += m_b1[0][g];
            partials[blockIdx.x] = s;
        }
    }
}

// ---------------- kernel 2: exact fp32 fixup (+ q patch, loss delta) ----------
__global__ __launch_bounds__(256)
void fixup_kernel(const float* __restrict__ z, const float* __restrict__ emb,
                  const float* __restrict__ enorm_g, const int* __restrict__ wl,
                  const int* __restrict__ wlcnt, float* __restrict__ idx_out,
                  float* __restrict__ q_out, float* __restrict__ wl_delta) {
    __shared__ float zrow[256];
    __shared__ float znred[4];
    __shared__ float mb[4];
    __shared__ int   mi[4];
    __shared__ int   fin_s;
    __shared__ float dred[4];

    const int t = threadIdx.x;
    const int l = t & 63, wv = t >> 6;
    const int dq = l & 3, tx = (l >> 2) & 15;

    int n = wlcnt[0];
    if (n > WLCAP) n = WLCAP;

#pragma unroll 1
    for (int i = blockIdx.x; i < n; i += 256) {
        const int r = wl[i];
        const float v = z[(size_t)r * 256 + t];
        zrow[t] = v;
        float zn = v * v;
#pragma unroll
        for (int o = 32; o > 0; o >>= 1) zn += __shfl_xor(zn, o);
        if (l == 0) znred[wv] = zn;
        __syncthreads();
        const float znf = (znred[0] + znred[1]) + (znred[2] + znred[3]);

        float b1 = 3.4e38f;
        int   i1 = 0;
#pragma unroll 1
        for (int cc = 0; cc < 16; ++cc) {
            const int c = wv * 256 + cc * 16 + tx;
            const float* er = emb + (size_t)c * 256 + dq * 4;
            float dot = 0.f;
#pragma unroll
            for (int j = 0; j < 16; ++j) {
                const float4 ev = *reinterpret_cast<const float4*>(er + j * 16);
                const float4 zv = *reinterpret_cast<const float4*>(&zrow[j * 16 + dq * 4]);
                dot = fmaf(zv.x, ev.x, dot);
                dot = fmaf(zv.y, ev.y, dot);
                dot = fmaf(zv.z, ev.z, dot);
                dot = fmaf(zv.w, ev.w, dot);
            }
            dot += __shfl_xor(dot, 1);
            dot += __shfl_xor(dot, 2);
            const float dist = fmaf(-2.f, dot, znf + enorm_g[c]);
            if (dist < b1) { b1 = dist; i1 = c; }
        }
#pragma unroll
        for (int off = 4; off < 64; off <<= 1) {
            const float ov = __shfl_xor(b1, off);
            const int   oi = __shfl_xor(i1, off);
            if (ov < b1 || (ov == b1 && oi < i1)) { b1 = ov; i1 = oi; }
        }
        if (l == 0) { mb[wv] = b1; mi[wv] = i1; }
        __syncthreads();
        if (t == 0) {
            float fb = mb[0]; int fi = mi[0];
#pragma unroll
            for (int g = 1; g < 4; ++g)
                if (mb[g] < fb || (mb[g] == fb && mi[g] < fi)) { fb = mb[g]; fi = mi[g]; }
            fin_s = fi;
        }
        __syncthreads();
        const int fi = fin_s;
        if (wl_delta != nullptr) {
            // fused mode: patch q + deterministic loss delta, then write idx
            const int oldi = (int)idx_out[r];
            float d = 0.f;
            if (fi != oldi) {
                const float en_ = emb[(size_t)fi * 256 + t];
                const float eo_ = emb[(size_t)oldi * 256 + t];
                const float zt = zrow[t];
                d = (en_ - zt) * (en_ - zt) - (eo_ - zt) * (eo_ - zt);
                q_out[(size_t)r * 256 + t] = en_;
            }
#pragma unroll
            for (int o = 32; o > 0; o >>= 1) d += __shfl_xor(d, o);
            if (l == 0) dred[wv] = d;
            __syncthreads();
            if (t == 0) {
                wl_delta[i] = (dred[0] + dred[1]) + (dred[2] + dred[3]);
                idx_out[r] = (float)fi;
            }
        } else {
            if (t == 0) idx_out[r] = (float)fi;
        }
        __syncthreads();   // LDS reused next iteration
    }
}

// ---------------- kernel 3 (fused path): loss = partials + deltas -------------
__global__ __launch_bounds__(256)
void loss_kernel(const float* __restrict__ partials, const float* __restrict__ wl_delta,
                 const int* __restrict__ wlcnt, float* __restrict__ loss_out) {
    const int tid = threadIdx.x;
    float s = partials[tid] + partials[tid + 256] + partials[tid + 512] + partials[tid + 768];
    int n = wlcnt[0];
    if (n > WLCAP) n = WLCAP;
    for (int i = tid; i < n; i += 256) s += wl_delta[i];
#pragma unroll
    for (int off = 32; off > 0; off >>= 1) s += __shfl_xor(s, off);
    __shared__ float red[4];
    if ((tid & 63) == 0) red[tid >> 6] = s;
    __syncthreads();
    if (tid == 0)
        loss_out[0] = ((red[0] + red[1]) + (red[2] + red[3])) * (1.25f / 16777216.0f);
}

// ---------------- fallback kernels (R13 flow, if ws too small) ----------------
__global__ __launch_bounds__(256)
void gather_kernel(const float* __restrict__ z, const float* __restrict__ emb,
                   const float* __restrict__ idx_f, float* __restrict__ q_out,
                   float* __restrict__ partials) {
    const int wv = threadIdx.x >> 6, ln = threadIdx.x & 63;
    float lsum = 0.f;
#pragma unroll
    for (int i = 0; i < 8; ++i) {
        const size_t row = (size_t)blockIdx.x * 32 + i * 4 + wv;
        const int kidx = (int)idx_f[row];
        const float4 e4 = *reinterpret_cast<const float4*>(emb + (size_t)kidx * 256 + ln * 4);
        const float4 z4 = *reinterpret_cast<const float4*>(z + row * 256 + ln * 4);
        *reinterpret_cast<float4*>(q_out + row * 256 + ln * 4) = e4;
        const float dx = e4.x - z4.x, dy = e4.y - z4.y, dz = e4.z - z4.z, dw = e4.w - z4.w;
        lsum += dx * dx + dy * dy + dz * dz + dw * dw;
    }
#pragma unroll
    for (int off = 32; off > 0; off >>= 1) lsum += __shfl_xor(lsum, off);
    __shared__ float red[4];
    if (ln == 0) red[wv] = lsum;
    __syncthreads();
    if (threadIdx.x == 0) partials[blockIdx.x] = red[0] + red[1] + red[2] + red[3];
}

__global__ __launch_bounds__(256)
void loss_fb_kernel(const float* __restrict__ partials, float* __restrict__ loss_out) {
    const int tid = threadIdx.x;
    float s = 0.f;
#pragma unroll
    for (int i = 0; i < 8; ++i) s += partials[tid + i * 256];
#pragma unroll
    for (int off = 32; off > 0; off >>= 1) s += __shfl_xor(s, off);
    __shared__ float red[4];
    if ((tid & 63) == 0) red[tid >> 6] = s;
    __syncthreads();
    if (tid == 0)
        loss_out[0] = (red[0] + red[1] + red[2] + red[3]) * (1.25f / 16777216.0f);
}

extern "C" void kernel_launch(void* const* d_in, const int* in_sizes, int n_in,
                              void* d_out, int out_size, void* d_ws, size_t ws_size,
                              hipStream_t stream) {
    const float* z   = (const float*)d_in[0];
    const float* emb = (const float*)d_in[1];
    float* out      = (float*)d_out;
    float* q_out    = out;                       // 16,777,216 floats
    float* loss_out = out + 16777216;            // 1 float
    float* idx_out  = out + 16777217;            // 65,536 floats

    // ws layout (floats): eh_t[131072] | el_t[131072] | enorm[1024] | partials[2048]
    //                     | wlcnt[64-pad] | wl[16384] | wl_delta[16384]
    const size_t WS_NEEDED = (size_t)298048 * 4;
    float* ws = (float*)d_ws;

    if (ws_size >= WS_NEEDED) {
        unsigned short* eh_t = (unsigned short*)ws;
        unsigned short* el_t = eh_t + 262144;
        float* enorm    = ws + 262144;
        float* partials = ws + 263168;
        int*   wlcnt    = (int*)(ws + 265216);
        int*   wl       = (int*)(ws + 265280);
        float* wl_delta = ws + 281664;

        eprep_kernel<<<1024, 256, 0, stream>>>(emb, eh_t, el_t, enorm, wlcnt);
        argmin_kernel<<<1024, 512, 0, stream>>>(z, eh_t, idx_out, wl, wlcnt,
                                                emb, q_out, partials);
        fixup_kernel<<<256, 256, 0, stream>>>(z, emb, enorm, wl, wlcnt, idx_out,
                                              q_out, wl_delta);
        loss_kernel<<<1, 256, 0, stream>>>(partials, wl_delta, wlcnt, loss_out);
    } else {
        // fallback: R13 flow, codebook scratch inside q (rewritten by gather)
        unsigned short* eh_t = (unsigned short*)q_out;
        unsigned short* el_t = eh_t + 262144;
        int*   wl    = (int*)(q_out + 262144);
        int*   wlcnt = (int*)(q_out + 327680);
        float* enorm    = ws;            // 1024
        float* partials = ws + 1024;     // 2048

        eprep_kernel<<<1024, 256, 0, stream>>>(emb, eh_t, el_t, enorm, wlcnt);
        argmin_kernel<<<1024, 512, 0, stream>>>(z, eh_t, idx_out, wl, wlcnt,
                                                emb, nullptr, nullptr);
        fixup_kernel<<<256, 256, 0, stream>>>(z, emb, enorm, wl, wlcnt, idx_out,
                                              nullptr, nullptr);
        gather_kernel<<<2048, 256, 0, stream>>>(z, emb, idx_out, q_out, partials);
        loss_fb_kernel<<<1, 256, 0, stream>>>(partials, loss_out);
    }
}

// Round 15
// 157.901 us; speedup vs baseline: 2.6432x; 1.0316x over previous
//
#include <hip/hip_runtime.h>
#include <stdint.h>

// VectorQuantizer — z:(16,256,64,64) f32 -> 65536 rows of 256; emb:(1024,256) f32.
// d_out: q[16777216] | vq_loss[1] | idx_as_float[65536]
//
// R15 = R14 with the register budget sized for 4 waves/SIMD: prefetch rotation
// 8->4 deep (R13 showed 8-deep buys nothing: latency isn't binding, overlap
// is) + __launch_bounds__(512,4) (VGPR cap 128: acc 64 + pf 32 + ~30 misc).
// R14 ran at 160 VGPR/thread -> 3 waves/SIMD -> pipes couldn't overlap.
// Spill signal = argmin WRITE_SIZE >> 66 MB (q output is ~66 MB clean).

typedef __attribute__((ext_vector_type(8))) short short8;
typedef __attribute__((ext_vector_type(16))) float f32x16;

#define THR_S 1e-3f     // s-space margin threshold (= 2e-3 in dist space)
#define WLCAP 16384

__device__ __forceinline__ unsigned short f2bf(float f) {
    const unsigned int x = __float_as_uint(f);
    return (unsigned short)((x + 0x7FFFu + ((x >> 16) & 1u)) >> 16);
}
__device__ __forceinline__ float bf2f(unsigned short h) {
    return __uint_as_float(((unsigned int)h) << 16);
}

#define MFMA32(A, B, C) __builtin_amdgcn_mfma_f32_32x32x16_bf16(A, B, C, 0, 0, 0)

// ---------------- kernel 0: e prep — transpose-split codebook + norms ----------
__global__ __launch_bounds__(256)
void eprep_kernel(const float* __restrict__ emb, unsigned short* __restrict__ eh_t,
                  unsigned short* __restrict__ el_t, float* __restrict__ enorm,
                  int* __restrict__ wlcnt) {
    const int code = blockIdx.x;
    const int k = threadIdx.x;
    if (code == 0 && k == 0) wlcnt[0] = 0;
    const float v = emb[code * 256 + k];
    const unsigned short h = f2bf(v);
    const int idx = ((k >> 4) << 14) + (code << 4) + (((k >> 3) & 1) << 3) + (k & 7);
    eh_t[idx] = h;
    el_t[idx] = f2bf(v - bf2f(h));
    float s = v * v;
#pragma unroll
    for (int o = 32; o > 0; o >>= 1) s += __shfl_xor(s, o);
    __shared__ float red[4];
    if ((k & 63) == 0) red[k >> 6] = s;
    __syncthreads();
    if (k == 0) enorm[code] = (red[0] + red[1]) + (red[2] + red[3]);
}

// ---------------- kernel 1: MFMA argmin + fused gather/loss ----------------
#define UPD(S, C, B1, I1, B2) { \
    const bool lt_ = (S) < B1; \
    B2 = lt_ ? B1 : fminf(B2, (S)); \
    I1 = lt_ ? (C) : I1; \
    B1 = lt_ ? (S) : B1; }

#define MERGE32(B1, I1, B2) { \
    const float ob1_ = __shfl_xor(B1, 32); \
    const int   oi1_ = __shfl_xor(I1, 32); \
    const float ob2_ = __shfl_xor(B2, 32); \
    const float nb2_ = fminf(fminf(B2, ob2_), fmaxf(B1, ob1_)); \
    if (ob1_ < B1 || (ob1_ == B1 && oi1_ < I1)) { B1 = ob1_; I1 = oi1_; } \
    B2 = nb2_; }

#define PFLOAD(S, U) { \
    const int un_ = (U) & 63; \
    const int ofs_ = ((un_ & 15) << 15) + ((un_ >> 4) << 10); \
    pf##S##h = *reinterpret_cast<const short8*>(ehp + ofs_); \
    pf##S##l = *reinterpret_cast<const short8*>(elp + ofs_); }

#define UNIT(S, KS) { \
    const int ko_ = (((KS) << 5) + (hi << 4)) ^ rsw; \
    const short8 bh0 = *reinterpret_cast<const short8*>(zbuf + rb0 + ko_); \
    const short8 bl0 = *reinterpret_cast<const short8*>(zbuf + 32768 + rb0 + ko_); \
    const short8 bh1 = *reinterpret_cast<const short8*>(zbuf + rb1 + ko_); \
    const short8 bl1 = *reinterpret_cast<const short8*>(zbuf + 32768 + rb1 + ko_); \
    acc1a = MFMA32(pf##S##h, bh0, acc1a); \
    acc1b = MFMA32(pf##S##h, bh1, acc1b); \
    acc2a = MFMA32(pf##S##h, bl0, acc2a); \
    acc2b = MFMA32(pf##S##h, bl1, acc2b); \
    acc2a = MFMA32(pf##S##l, bh0, acc2a); \
    acc2b = MFMA32(pf##S##l, bh1, acc2b); }

__global__ __launch_bounds__(512, 4)
void argmin_kernel(const float* __restrict__ z, const unsigned short* __restrict__ eh_t,
                   float* __restrict__ idx_out, int* __restrict__ wl,
                   int* __restrict__ wlcnt, const float* __restrict__ emb,
                   float* __restrict__ q_out, float* __restrict__ partials) {
    __shared__ char zbuf[65536];          // zh 32K | zl 32K: byte = row*512 + (2k ^ ((row&7)<<4))
    __shared__ float m_b1[8][64];
    __shared__ int   m_i1[8][64];
    __shared__ float m_b2[8][64];
    __shared__ int   fidx_s[64];

    const int t = threadIdx.x;
    const int l = t & 63;
    const int w = t >> 6;
    const int cl = l & 31;
    const int hi = l >> 5;

    const float* zblk = z + (size_t)blockIdx.x * 16384;

    // ---- stage z: fp32 -> bf16 hi/lo into swizzled LDS (once) ----
#pragma unroll
    for (int i = 0; i < 8; ++i) {
        const int idx = i * 2048 + t * 4;
        const int row = idx >> 8, k = idx & 255;
        const float4 v = *reinterpret_cast<const float4*>(zblk + idx);
        ushort4 hv, lv;
        hv.x = f2bf(v.x); lv.x = f2bf(v.x - bf2f(hv.x));
        hv.y = f2bf(v.y); lv.y = f2bf(v.y - bf2f(hv.y));
        hv.z = f2bf(v.z); lv.z = f2bf(v.z - bf2f(hv.z));
        hv.w = f2bf(v.w); lv.w = f2bf(v.w - bf2f(hv.w));
        const int boff = row * 512 + ((k << 1) ^ ((row & 7) << 4));
        *reinterpret_cast<ushort4*>(zbuf + boff) = hv;
        *reinterpret_cast<ushort4*>(zbuf + 32768 + boff) = lv;
    }
    __syncthreads();

    const char* ehp = (const char*)eh_t + (w * 128 + cl) * 32 + hi * 16;
    const char* elp = ehp + 524288;

    const int rb0 = cl * 512;
    const int rb1 = rb0 + 16384;
    const int rsw = (cl & 7) << 4;

    f32x16 acc1a, acc2a, acc1b, acc2b;
#pragma unroll
    for (int j = 0; j < 16; ++j) { acc1a[j] = 0.f; acc2a[j] = 0.f; acc1b[j] = 0.f; acc2b[j] = 0.f; }

    float b1a = 3.4e38f, b2a = 3.4e38f, b1b = 3.4e38f, b2b = 3.4e38f;
    int   i1a = 0, i1b = 0;

    short8 pf0h, pf0l, pf1h, pf1l, pf2h, pf2l, pf3h, pf3l;
    PFLOAD(0, 0) PFLOAD(1, 1) PFLOAD(2, 2) PFLOAD(3, 3)

#pragma unroll 1
    for (int ct = 0; ct < 4; ++ct) {
#pragma unroll 1
        for (int j = 0; j < 4; ++j) {
            const int u0 = (ct << 4) + (j << 2);
            UNIT(0, ((j << 2) + 0)) PFLOAD(0, u0 + 4)
            UNIT(1, ((j << 2) + 1)) PFLOAD(1, u0 + 5)
            UNIT(2, ((j << 2) + 2)) PFLOAD(2, u0 + 6)
            UNIT(3, ((j << 2) + 3)) PFLOAD(3, u0 + 7)
        }
        const int code0 = w * 128 + (ct << 5) + (hi << 2);
#pragma unroll
        for (int reg = 0; reg < 16; ++reg) {
            const int code = code0 + (reg & 3) + ((reg >> 2) << 3);
            const float s0 = -(acc1a[reg] + acc2a[reg]);
            const float s1 = -(acc1b[reg] + acc2b[reg]);
            UPD(s0, code, b1a, i1a, b2a)
            UPD(s1, code, b1b, i1b, b2b)
            acc1a[reg] = 0.f; acc2a[reg] = 0.f; acc1b[reg] = 0.f; acc2b[reg] = 0.f;
        }
    }

    MERGE32(b1a, i1a, b2a)
    MERGE32(b1b, i1b, b2b)
    if (l < 32) {
        m_b1[w][cl] = b1a;      m_i1[w][cl] = i1a;      m_b2[w][cl] = b2a;
        m_b1[w][cl + 32] = b1b; m_i1[w][cl + 32] = i1b; m_b2[w][cl + 32] = b2b;
    }
    __syncthreads();
    if (t < 64) {
        float b1 = m_b1[0][t]; int i1 = m_i1[0][t]; float b2 = m_b2[0][t];
#pragma unroll
        for (int g = 1; g < 8; ++g) {
            const float ob1 = m_b1[g][t]; const int oi1 = m_i1[g][t]; const float ob2 = m_b2[g][t];
            const float nb2 = fminf(fminf(b2, ob2), fmaxf(b1, ob1));
            if (ob1 < b1 || (ob1 == b1 && oi1 < i1)) { b1 = ob1; i1 = oi1; }
            b2 = nb2;
        }
        const int grow = blockIdx.x * 64 + t;
        idx_out[grow] = (float)i1;
        fidx_s[t] = i1;
        if (b2 - b1 < THR_S) {
            const int pos = atomicAdd(wlcnt, 1);
            if (pos < WLCAP) wl[pos] = grow;
        }
    }

    // ---- fused gather + loss partial (skipped in fallback mode) ----
    if (q_out != nullptr) {
        __syncthreads();   // fidx_s visible
        float lsum = 0.f;
        float* qblk = q_out + (size_t)blockIdx.x * 16384;
#pragma unroll
        for (int i = 0; i < 8; ++i) {
            const int row = i * 8 + w;     // wave w handles row i*8+w (uniform)
            const int code = fidx_s[row];
            const float4 e4 = *reinterpret_cast<const float4*>(
                emb + (size_t)code * 256 + l * 4);
            const int byt = row * 512 + ((l * 8) ^ ((row & 7) << 4));
            const ushort4 h4 = *reinterpret_cast<const ushort4*>(zbuf + byt);
            const ushort4 l4 = *reinterpret_cast<const ushort4*>(zbuf + 32768 + byt);
            const float zx = bf2f(h4.x) + bf2f(l4.x);
            const float zy = bf2f(h4.y) + bf2f(l4.y);
            const float zz = bf2f(h4.z) + bf2f(l4.z);
            const float zw = bf2f(h4.w) + bf2f(l4.w);
            const float dx = e4.x - zx, dy = e4.y - zy, dz = e4.z - zz, dw = e4.w - zw;
            lsum += dx * dx + dy * dy + dz * dz + dw * dw;
            *reinterpret_cast<float4*>(qblk + row * 256 + l * 4) = e4;
        }
#pragma unroll
        for (int o = 32; o > 0; o >>= 1) lsum += __shfl_xor(lsum, o);
        if (l == 0) m_b1[0][w] = lsum;    // reuse merge LDS as scratch
        __syncthreads();
        if (t == 0) {
            float s = 0.f;
#pragma unroll
            for (int g = 0; g < 8; ++g) s += m_b1[0][g];
            partials[blockIdx.x] = s;
        }
    }
}

// ---------------- kernel 2: exact fp32 fixup (+ q patch, loss delta) ----------
__global__ __launch_bounds__(256)
void fixup_kernel(const float* __restrict__ z, const float* __restrict__ emb,
                  const float* __restrict__ enorm_g, const int* __restrict__ wl,
                  const int* __restrict__ wlcnt, float* __restrict__ idx_out,
                  float* __restrict__ q_out, float* __restrict__ wl_delta) {
    __shared__ float zrow[256];
    __shared__ float znred[4];
    __shared__ float mb[4];
    __shared__ int   mi[4];
    __shared__ int   fin_s;
    __shared__ float dred[4];

    const int t = threadIdx.x;
    const int l = t & 63, wv = t >> 6;
    const int dq = l & 3, tx = (l >> 2) & 15;

    int n = wlcnt[0];
    if (n > WLCAP) n = WLCAP;

#pragma unroll 1
    for (int i = blockIdx.x; i < n; i += 256) {
        const int r = wl[i];
        const float v = z[(size_t)r * 256 + t];
        zrow[t] = v;
        float zn = v * v;
#pragma unroll
        for (int o = 32; o > 0; o >>= 1) zn += __shfl_xor(zn, o);
        if (l == 0) znred[wv] = zn;
        __syncthreads();
        const float znf = (znred[0] + znred[1]) + (znred[2] + znred[3]);

        float b1 = 3.4e38f;
        int   i1 = 0;
#pragma unroll 1
        for (int cc = 0; cc < 16; ++cc) {
            const int c = wv * 256 + cc * 16 + tx;
            const float* er = emb + (size_t)c * 256 + dq * 4;
            float dot = 0.f;
#pragma unroll
            for (int j = 0; j < 16; ++j) {
                const float4 ev = *reinterpret_cast<const float4*>(er + j * 16);
                const float4 zv = *reinterpret_cast<const float4*>(&zrow[j * 16 + dq * 4]);
                dot = fmaf(zv.x, ev.x, dot);
                dot = fmaf(zv.y, ev.y, dot);
                dot = fmaf(zv.z, ev.z, dot);
                dot = fmaf(zv.w, ev.w, dot);
            }
            dot += __shfl_xor(dot, 1);
            dot += __shfl_xor(dot, 2);
            const float dist = fmaf(-2.f, dot, znf + enorm_g[c]);
            if (dist < b1) { b1 = dist; i1 = c; }
        }
#pragma unroll
        for (int off = 4; off < 64; off <<= 1) {
            const float ov = __shfl_xor(b1, off);
            const int   oi = __shfl_xor(i1, off);
            if (ov < b1 || (ov == b1 && oi < i1)) { b1 = ov; i1 = oi; }
        }
        if (l == 0) { mb[wv] = b1; mi[wv] = i1; }
        __syncthreads();
        if (t == 0) {
            float fb = mb[0]; int fi = mi[0];
#pragma unroll
            for (int g = 1; g < 4; ++g)
                if (mb[g] < fb || (mb[g] == fb && mi[g] < fi)) { fb = mb[g]; fi = mi[g]; }
            fin_s = fi;
        }
        __syncthreads();
        const int fi = fin_s;
        if (wl_delta != nullptr) {
            const int oldi = (int)idx_out[r];
            float d = 0.f;
            if (fi != oldi) {
                const float en_ = emb[(size_t)fi * 256 + t];
                const float eo_ = emb[(size_t)oldi * 256 + t];
                const float zt = zrow[t];
                d = (en_ - zt) * (en_ - zt) - (eo_ - zt) * (eo_ - zt);
                q_out[(size_t)r * 256 + t] = en_;
            }
#pragma unroll
            for (int o = 32; o > 0; o >>= 1) d += __shfl_xor(d, o);
            if (l == 0) dred[wv] = d;
            __syncthreads();
            if (t == 0) {
                wl_delta[i] = (dred[0] + dred[1]) + (dred[2] + dred[3]);
                idx_out[r] = (float)fi;
            }
        } else {
            if (t == 0) idx_out[r] = (float)fi;
        }
        __syncthreads();   // LDS reused next iteration
    }
}

// ---------------- kernel 3 (fused path): loss = partials + deltas -------------
__global__ __launch_bounds__(256)
void loss_kernel(const float* __restrict__ partials, const float* __restrict__ wl_delta,
                 const int* __restrict__ wlcnt, float* __restrict__ loss_out) {
    const int tid = threadIdx.x;
    float s = partials[tid] + partials[tid + 256] + partials[tid + 512] + partials[tid + 768];
    int n = wlcnt[0];
    if (n > WLCAP) n = WLCAP;
    for (int i = tid; i < n; i += 256) s += wl_delta[i];
#pragma unroll
    for (int off = 32; off > 0; off >>= 1) s += __shfl_xor(s, off);
    __shared__ float red[4];
    if ((tid & 63) == 0) red[tid >> 6] = s;
    __syncthreads();
    if (tid == 0)
        loss_out[0] = ((red[0] + red[1]) + (red[2] + red[3])) * (1.25f / 16777216.0f);
}

// ---------------- fallback kernels (R13 flow, if ws too small) ----------------
__global__ __launch_bounds__(256)
void gather_kernel(const float* __restrict__ z, const float* __restrict__ emb,
                   const float* __restrict__ idx_f, float* __restrict__ q_out,
                   float* __restrict__ partials) {
    const int wv = threadIdx.x >> 6, ln = threadIdx.x & 63;
    float lsum = 0.f;
#pragma unroll
    for (int i = 0; i < 8; ++i) {
        const size_t row = (size_t)blockIdx.x * 32 + i * 4 + wv;
        const int kidx = (int)idx_f[row];
        const float4 e4 = *reinterpret_cast<const float4*>(emb + (size_t)kidx * 256 + ln * 4);
        const float4 z4 = *reinterpret_cast<const float4*>(z + row * 256 + ln * 4);
        *reinterpret_cast<float4*>(q_out + row * 256 + ln * 4) = e4;
        const float dx = e4.x - z4.x, dy = e4.y - z4.y, dz = e4.z - z4.z, dw = e4.w - z4.w;
        lsum += dx * dx + dy * dy + dz * dz + dw * dw;
    }
#pragma unroll
    for (int off = 32; off > 0; off >>= 1) lsum += __shfl_xor(lsum, off);
    __shared__ float red[4];
    if (ln == 0) red[wv] = lsum;
    __syncthreads();
    if (threadIdx.x == 0) partials[blockIdx.x] = red[0] + red[1] + red[2] + red[3];
}

__global__ __launch_bounds__(256)
void loss_fb_kernel(const float* __restrict__ partials, float* __restrict__ loss_out) {
    const int tid = threadIdx.x;
    float s = 0.f;
#pragma unroll
    for (int i = 0; i < 8; ++i) s += partials[tid + i * 256];
#pragma unroll
    for (int off = 32; off > 0; off >>= 1) s += __shfl_xor(s, off);
    __shared__ float red[4];
    if ((tid & 63) == 0) red[tid >> 6] = s;
    __syncthreads();
    if (tid == 0)
        loss_out[0] = (red[0] + red[1] + red[2] + red[3]) * (1.25f / 16777216.0f);
}

extern "C" void kernel_launch(void* const* d_in, const int* in_sizes, int n_in,
                              void* d_out, int out_size, void* d_ws, size_t ws_size,
                              hipStream_t stream) {
    const float* z   = (const float*)d_in[0];
    const float* emb = (const float*)d_in[1];
    float* out      = (float*)d_out;
    float* q_out    = out;                       // 16,777,216 floats
    float* loss_out = out + 16777216;            // 1 float
    float* idx_out  = out + 16777217;            // 65,536 floats

    // ws layout (floats): eh_t[131072] | el_t[131072] | enorm[1024] | partials[2048]
    //                     | wlcnt[64-pad] | wl[16384] | wl_delta[16384]
    const size_t WS_NEEDED = (size_t)298048 * 4;
    float* ws = (float*)d_ws;

    if (ws_size >= WS_NEEDED) {
        unsigned short* eh_t = (unsigned short*)ws;
        unsigned short* el_t = eh_t + 262144;
        float* enorm    = ws + 262144;
        float* partials = ws + 263168;
        int*   wlcnt    = (int*)(ws + 265216);
        int*   wl       = (int*)(ws + 265280);
        float* wl_delta = ws + 281664;

        eprep_kernel<<<1024, 256, 0, stream>>>(emb, eh_t, el_t, enorm, wlcnt);
        argmin_kernel<<<1024, 512, 0, stream>>>(z, eh_t, idx_out, wl, wlcnt,
                                                emb, q_out, partials);
        fixup_kernel<<<256, 256, 0, stream>>>(z, emb, enorm, wl, wlcnt, idx_out,
                                              q_out, wl_delta);
        loss_kernel<<<1, 256, 0, stream>>>(partials, wl_delta, wlcnt, loss_out);
    } else {
        // fallback: R13 flow, codebook scratch inside q (rewritten by gather)
        unsigned short* eh_t = (unsigned short*)q_out;
        unsigned short* el_t = eh_t + 262144;
        int*   wl    = (int*)(q_out + 262144);
        int*   wlcnt = (int*)(q_out + 327680);
        float* enorm    = ws;            // 1024
        float* partials = ws + 1024;     // 2048

        eprep_kernel<<<1024, 256, 0, stream>>>(emb, eh_t, el_t, enorm, wlcnt);
        argmin_kernel<<<1024, 512, 0, stream>>>(z, eh_t, idx_out, wl, wlcnt,
                                                emb, nullptr, nullptr);
        fixup_kernel<<<256, 256, 0, stream>>>(z, emb, enorm, wl, wlcnt, idx_out,
                                              nullptr, nullptr);
        gather_kernel<<<2048, 256, 0, stream>>>(z, emb, idx_out, q_out, partials);
        loss_fb_kernel<<<1, 256, 0, stream>>>(partials, loss_out);
    }
}